// Round 8
// baseline (224.751 us; speedup 1.0000x reference)
//
#include <hip/hip_runtime.h>
#include <math.h>

// ---------------------------------------------------------------------------
// DeepBilateralNetCurves (HDRNet) forward, f32.
// B=2, lowres 3x256x256, fullres 3x1024x1024, grid 12x8x16x16, 16-pt curve.
//
// Round 7 post-mortem: apply_k (fc12+pred fused, 64x64 tiles) was 100us at
// 10.8% occupancy -- 512 blocks with a long serial preamble. Round 8:
//  - pred_k: fc1+fc2+pred -> sco in workspace (64 blocks, LDS-staged pw/loc1)
//  - apply_k: 32x32-px tiles (2048 blocks). A 32x32 tile has constant
//    (fy,fx), so the slice footprint is exactly 2x2 cells = 1.5KB LDS.
// 9 launches: conv0..conv3, gl0, gl1, fc0, pred, apply.
// ---------------------------------------------------------------------------

static inline int cdiv(int a, int b) { return (a + b - 1) / b; }

// ---- wide naive 3x3 convs (small Cin) --------------------------------------

__global__ void conv3x3_chw_k(const float* __restrict__ in, const float* __restrict__ wgt,
                              const float* __restrict__ bias, float* __restrict__ out,
                              int B, int Cin, int Hin, int Win,
                              int Cout, int Hout, int Wout, int stride) {
    int total = B * Cout * Hout * Wout;
    int idx = blockIdx.x * blockDim.x + threadIdx.x;
    if (idx >= total) return;
    int wo = idx % Wout;
    int ho = (idx / Wout) % Hout;
    int co = (idx / (Wout * Hout)) % Cout;
    int b  = idx / (Wout * Hout * Cout);
    float acc = bias[co];
    int hb = ho * stride - 1, wb = wo * stride - 1;
    const float* wr = wgt + (size_t)co * Cin * 9;
    const float* ib = in + (size_t)b * Cin * Hin * Win;
    for (int ci = 0; ci < Cin; ++ci) {
        const float* ip = ib + (size_t)ci * Hin * Win;
        const float* wp = wr + ci * 9;
#pragma unroll
        for (int ky = 0; ky < 3; ++ky) {
            int hi = hb + ky;
            if (hi < 0 || hi >= Hin) continue;
#pragma unroll
            for (int kx = 0; kx < 3; ++kx) {
                int wi = wb + kx;
                if (wi < 0 || wi >= Win) continue;
                acc += ip[hi * Win + wi] * wp[ky * 3 + kx];
            }
        }
    }
    out[idx] = fmaxf(acc, 0.0f);
}

__global__ void conv3x3_hwc_k(const float* __restrict__ in, const float* __restrict__ wgt,
                              const float* __restrict__ bias, float* __restrict__ out,
                              int B, int Cin, int Hin, int Win,
                              int Cout, int Hout, int Wout, int stride) {
    int total = B * Cout * Hout * Wout;
    int idx = blockIdx.x * blockDim.x + threadIdx.x;
    if (idx >= total) return;
    int co = idx % Cout;
    int wo = (idx / Cout) % Wout;
    int ho = (idx / (Cout * Wout)) % Hout;
    int b  = idx / (Cout * Wout * Hout);
    float acc = bias[co];
    int hb = ho * stride - 1, wb = wo * stride - 1;
    const float* wr = wgt + (size_t)co * Cin * 9;
    const float* ib = in + (size_t)b * Cin * Hin * Win;
    for (int ci = 0; ci < Cin; ++ci) {
        const float* ip = ib + (size_t)ci * Hin * Win;
        const float* wp = wr + ci * 9;
#pragma unroll
        for (int ky = 0; ky < 3; ++ky) {
            int hi = hb + ky;
            if (hi < 0 || hi >= Hin) continue;
#pragma unroll
            for (int kx = 0; kx < 3; ++kx) {
                int wi = wb + kx;
                if (wi < 0 || wi >= Win) continue;
                acc += ip[hi * Win + wi] * wp[ky * 3 + kx];
            }
        }
    }
    out[idx] = fmaxf(acc, 0.0f);  // idx == HWC flat index
}

// ---- wave-per-output conv (HWC input, lane = ci) ---------------------------

__device__ __forceinline__ void wave_conv_one(
    const float* __restrict__ in, const float* __restrict__ wgt,
    const float* __restrict__ bias, float* __restrict__ out,
    int B, int Cin, int Hin, int Win, int Cout, int Hout, int Wout,
    int stride, int relu, int out_chw, int wid, int lane) {
    int copw = (Cin == 64) ? 1 : 2;
    int cow  = Cout / copw;
    int ci   = lane & (Cin - 1);
    int cw = wid % cow;
    int wo = (wid / cow) % Wout;
    int ho = (wid / (cow * Wout)) % Hout;
    int b  = wid / (cow * Wout * Hout);
    int co = cw * copw + ((copw == 2) ? (lane >> 5) : 0);
    int hb = ho * stride - 1, wb = wo * stride - 1;
    const float* wp = wgt + ((size_t)co * Cin + ci) * 9;
    float acc = 0.0f;
#pragma unroll
    for (int ky = 0; ky < 3; ++ky) {
        int hi = hb + ky;
        if (hi < 0 || hi >= Hin) continue;
#pragma unroll
        for (int kx = 0; kx < 3; ++kx) {
            int wi = wb + kx;
            if (wi < 0 || wi >= Win) continue;
            acc += in[((size_t)(b * Hin + hi) * Win + wi) * Cin + ci] * wp[ky * 3 + kx];
        }
    }
    for (int m = 1; m < Cin; m <<= 1) acc += __shfl_xor(acc, m);
    if (ci == 0) {
        if (bias) acc += bias[co];
        if (relu) acc = fmaxf(acc, 0.0f);
        if (out_chw) out[((size_t)(b * Cout + co) * Hout + ho) * Wout + wo] = acc;
        else         out[((size_t)(b * Hout + ho) * Wout + wo) * Cout + co] = acc;
    }
}

// conv3: 32->64, 32x32 -> 16x16, stride 2, HWC->HWC
__global__ void conv3_k(const float* __restrict__ x2, const float* __restrict__ w,
                        const float* __restrict__ bias, float* __restrict__ x3, int B) {
    int tid = blockIdx.x * blockDim.x + threadIdx.x;
    int wid = tid >> 6, lane = threadIdx.x & 63;
    int nw = B * 32 * 16 * 16;
    if (wid >= nw) return;
    wave_conv_one(x2, w, bias, x3, B, 32, 32, 32, 64, 16, 16, 2, 1, 0, wid, lane);
}

// gconv0 (64ch 16->8, s2) || lconv0 (64ch 16x16, s1, relu)
__global__ void gl0_k(const float* __restrict__ x3,
                      const float* __restrict__ gw, const float* __restrict__ gb, float* __restrict__ g0,
                      const float* __restrict__ lw, const float* __restrict__ lb, float* __restrict__ loc0,
                      int B) {
    int tid = blockIdx.x * blockDim.x + threadIdx.x;
    int wid = tid >> 6, lane = threadIdx.x & 63;
    int ng = B * 64 * 8 * 8;
    int nl = B * 64 * 16 * 16;
    if (wid < ng)            wave_conv_one(x3, gw, gb, g0,  B, 64, 16, 16, 64, 8, 8,  2, 1, 0, wid, lane);
    else if (wid < ng + nl)  wave_conv_one(x3, lw, lb, loc0, B, 64, 16, 16, 64, 16, 16, 1, 1, 0, wid - ng, lane);
}

// gconv1 (64ch 8->4, s2, CHW out for FC flatten) || lconv1 (no relu)
__global__ void gl1_k(const float* __restrict__ g0, const float* __restrict__ loc0,
                      const float* __restrict__ gw, const float* __restrict__ gb, float* __restrict__ g1,
                      const float* __restrict__ lw, float* __restrict__ loc1, int B) {
    int tid = blockIdx.x * blockDim.x + threadIdx.x;
    int wid = tid >> 6, lane = threadIdx.x & 63;
    int ng = B * 64 * 4 * 4;
    int nl = B * 64 * 16 * 16;
    if (wid < ng)            wave_conv_one(g0, gw, gb, g1,   B, 64, 8, 8,  64, 4, 4,  2, 1, 1, wid, lane);
    else if (wid < ng + nl)  wave_conv_one(loc0, lw, nullptr, loc1, B, 64, 16, 16, 64, 16, 16, 1, 0, 0, wid - ng, lane);
}

// fc0: wave per (b,o), 1024-dot, relu. out f0[b*256+o].
__global__ void fc0_k(const float* __restrict__ g1, const float* __restrict__ fw0,
                      const float* __restrict__ fb0, float* __restrict__ f0, int B) {
    int tid  = blockIdx.x * blockDim.x + threadIdx.x;
    int wid  = tid >> 6;
    int lane = threadIdx.x & 63;
    if (wid >= B * 256) return;
    int o = wid & 255, b = wid >> 8;
    const float* ip = g1 + (size_t)b * 1024;
    const float* wp = fw0 + (size_t)o * 1024;
    float acc = 0.0f;
    for (int j = lane; j < 1024; j += 64) acc += ip[j] * wp[j];
    for (int m = 1; m < 64; m <<= 1) acc += __shfl_xor(acc, m);
    if (lane == 0) f0[wid] = fmaxf(acc + fb0[o], 0.0f);
}

// ---- pred_k: fc1 + fc2 (per-block redundant) + grid coeffs -> sco ----------
// grid = B*32 blocks x 256 thr; each block computes 8 cells x 96 channels.
// sco layout: sco[b*24576 + cell*96 + z*12 + c], cell = y*16+x.
__global__ __launch_bounds__(256) void pred_k(
    const float* __restrict__ f0g,
    const float* __restrict__ fw1, const float* __restrict__ fb1,
    const float* __restrict__ fw2, const float* __restrict__ fb2,
    const float* __restrict__ loc1,
    const float* __restrict__ pw, const float* __restrict__ pb,
    float* __restrict__ sco) {
    __shared__ float s_pw[96 * 65];
    __shared__ float s_pb[96];
    __shared__ float s_f0[256];
    __shared__ float s_f1[128];
    __shared__ float s_f2[64];
    __shared__ __align__(16) float s_loc[8 * 64];

    const int t    = threadIdx.x;
    const int b    = blockIdx.x >> 5;
    const int part = blockIdx.x & 31;       // 8 cells per part
    const int wl   = t >> 6;
    const int lane = t & 63;

    // stage pw (padded rows), pb, f0, loc1 cells
    {
        const float4* pw4 = (const float4*)pw;  // 1536 float4
        for (int j = t; j < 1536; j += 256) {
            float4 v = pw4[j];
            int base = j * 4;
            int c = base >> 6, i = base & 63;
            float* dst = &s_pw[c * 65 + i];
            dst[0] = v.x; dst[1] = v.y; dst[2] = v.z; dst[3] = v.w;
        }
        s_f0[t] = f0g[b * 256 + t];
        if (t < 96) s_pb[t] = pb[t];
        if (t < 128) {  // 8 cells x 64 ch = 128 float4
            int cell = t >> 4, i4 = t & 15;
            float4 v = ((const float4*)(loc1 + ((size_t)(b * 256 + part * 8 + cell)) * 64))[i4];
            ((float4*)(s_loc + cell * 64))[i4] = v;
        }
    }
    __syncthreads();

    // fc1: 128 outputs, wave-dots over s_f0 (weights L2-hot)
    for (int o = wl; o < 128; o += 4) {
        const float* wp = fw1 + (size_t)o * 256;
        float acc = 0.0f;
#pragma unroll
        for (int j = lane; j < 256; j += 64) acc += s_f0[j] * wp[j];
        for (int m = 1; m < 64; m <<= 1) acc += __shfl_xor(acc, m);
        if (lane == 0) s_f1[o] = fmaxf(acc + fb1[o], 0.0f);
    }
    __syncthreads();
    // fc2: 64 outputs (no relu)
    for (int o = wl; o < 64; o += 4) {
        const float* wp = fw2 + (size_t)o * 128;
        float acc = 0.0f;
#pragma unroll
        for (int j = lane; j < 128; j += 64) acc += s_f1[j] * wp[j];
        for (int m = 1; m < 64; m <<= 1) acc += __shfl_xor(acc, m);
        if (lane == 0) s_f2[o] = acc + fb2[o];
    }
    __syncthreads();

    // pred: 768 outputs per block, 3 per thread
#pragma unroll
    for (int k = 0; k < 3; ++k) {
        int v = k * 256 + t;            // 0..767
        int lcell = v / 96;             // 0..7
        int c = v % 96;
        const float* wp = &s_pw[c * 65];
        const float* lp = &s_loc[lcell * 64];
        float acc = s_pb[c];
        for (int i = 0; i < 64; ++i)
            acc += wp[i] * fmaxf(s_f2[i] + lp[i], 0.0f);
        sco[(size_t)b * 24576 + part * 768 + v] = acc;
    }
}

// ---- apply_k: guide + trilinear slice + affine apply -----------------------
// One block per 32x32-px tile (grid = B*1024). A 32x32 tile has constant
// (fy,fx) -> slice footprint is exactly 2x2 cells, staged in 1.5KB LDS.
__global__ __launch_bounds__(256) void apply_k(
    const float* __restrict__ img, const float* __restrict__ sco,
    const float* __restrict__ ccm_w, const float* __restrict__ ccm_b,
    const float* __restrict__ shifts, const float* __restrict__ slopes,
    const float* __restrict__ proj_w, const float* __restrict__ proj_b,
    float* __restrict__ out) {
    __shared__ __align__(16) float s_sco[4 * 96];   // 2x2 cells x (z*12+c)
    __shared__ float s_shift[48], s_slope[48], s_ccmw[9], s_ccmb[3], s_projw[3], s_projb[1];

    const int t   = threadIdx.x;
    const int b   = blockIdx.x >> 10;
    const int rem = blockIdx.x & 1023;
    const int ty  = rem >> 5;           // 0..31 (32-px rows)
    const int tx  = rem & 31;           // 0..31 (32-px cols)
    const int fy0 = (ty - 1) >> 1;      // constant floor(ys) over the tile
    const int fx0 = (tx - 1) >> 1;

    // stage 2x2 cells (96 floats each = 24 float4) + params
    if (t < 96) {
        int cell = t >> 5 ? (t / 24) : (t / 24);    // 0..3
        cell = t / 24;
        int i4 = t % 24;
        int dy = cell >> 1, dx = cell & 1;
        int gy = min(max(fy0 + dy, 0), 15);
        int gx = min(max(fx0 + dx, 0), 15);
        float4 v = ((const float4*)(sco + ((size_t)b * 256 + gy * 16 + gx) * 96))[i4];
        ((float4*)(s_sco + cell * 96))[i4] = v;
    }
    if (t >= 128 && t < 176) { int j = t - 128; s_shift[j] = shifts[j]; s_slope[j] = slopes[j]; }
    if (t >= 192 && t < 201) s_ccmw[t - 192] = ccm_w[t - 192];
    if (t >= 208 && t < 211) { s_ccmb[t - 208] = ccm_b[t - 208]; s_projw[t - 208] = proj_w[t - 208]; }
    if (t == 224) s_projb[0] = proj_b[0];
    __syncthreads();

    const size_t plane = 1024 * 1024;
    const float* ibase = img + (size_t)b * 3 * plane;
    float* obase = out + (size_t)b * 3 * plane;
#pragma unroll
    for (int it = 0; it < 4; ++it) {
        int pxi = it * 256 + t;
        int row = pxi >> 5, col = pxi & 31;
        int y = ty * 32 + row, x = tx * 32 + col;
        size_t off = (size_t)y * 1024 + x;
        float r  = ibase[off];
        float g  = ibase[plane + off];
        float bl = ibase[2 * plane + off];

        float gd = s_projb[0];
#pragma unroll
        for (int c = 0; c < 3; ++c) {
            float v = s_ccmb[c] + s_ccmw[c * 3 + 0] * r + s_ccmw[c * 3 + 1] * g + s_ccmw[c * 3 + 2] * bl;
            float acc = 0.0f;
#pragma unroll
            for (int p = 0; p < 16; ++p)
                acc += s_slope[c * 16 + p] * fmaxf(v - s_shift[c * 16 + p], 0.0f);
            gd += s_projw[c] * acc;
        }
        gd = fminf(fmaxf(gd, 0.0f), 1.0f);

        float xs = ((float)x + 0.5f) * 0.015625f - 0.5f;
        float ys = ((float)y + 0.5f) * 0.015625f - 0.5f;
        float gz = gd * 8.0f - 0.5f;
        int fx = (int)floorf(xs);       // == fx0
        int fy = (int)floorf(ys);       // == fy0
        int fz = (int)floorf(gz);

        float coeff[12];
#pragma unroll
        for (int c = 0; c < 12; ++c) coeff[c] = 0.0f;

#pragma unroll
        for (int dz = 0; dz < 2; ++dz) {
            int zi = min(max(fz + dz, 0), 7);
            float wz = fmaxf(1.0f - fabsf(gz - (float)(fz + dz)), 0.0f);
#pragma unroll
            for (int dy = 0; dy < 2; ++dy) {
                int ly = min(max(fy + dy - fy0, 0), 1);
                float wy = fmaxf(1.0f - fabsf(ys - (float)(fy + dy)), 0.0f);
#pragma unroll
                for (int dx = 0; dx < 2; ++dx) {
                    int lx = min(max(fx + dx - fx0, 0), 1);
                    float wx = fmaxf(1.0f - fabsf(xs - (float)(fx + dx)), 0.0f);
                    float wt = wz * wy * wx;
                    const float4* gp = (const float4*)(s_sco + ((ly * 2 + lx) * 96 + zi * 12));
                    float4 a0 = gp[0], a1 = gp[1], a2 = gp[2];
                    coeff[0]  += wt * a0.x; coeff[1]  += wt * a0.y; coeff[2]  += wt * a0.z; coeff[3]  += wt * a0.w;
                    coeff[4]  += wt * a1.x; coeff[5]  += wt * a1.y; coeff[6]  += wt * a1.z; coeff[7]  += wt * a1.w;
                    coeff[8]  += wt * a2.x; coeff[9]  += wt * a2.y; coeff[10] += wt * a2.z; coeff[11] += wt * a2.w;
                }
            }
        }

#pragma unroll
        for (int o = 0; o < 3; ++o) {
            float v = coeff[o * 4 + 3] + coeff[o * 4 + 0] * r + coeff[o * 4 + 1] * g + coeff[o * 4 + 2] * bl;
            obase[o * plane + off] = fminf(fmaxf(v, 0.0f), 1.0f);
        }
    }
}

// ---------------------------------------------------------------------------

extern "C" void kernel_launch(void* const* d_in, const int* in_sizes, int n_in,
                              void* d_out, int out_size, void* d_ws, size_t ws_size,
                              hipStream_t stream) {
    const float* img_lo = (const float*)d_in[0];
    const float* img_fr = (const float*)d_in[1];
    const float* sw0 = (const float*)d_in[2];  const float* sb0 = (const float*)d_in[3];
    const float* sw1 = (const float*)d_in[4];  const float* sb1 = (const float*)d_in[5];
    const float* sw2 = (const float*)d_in[6];  const float* sb2 = (const float*)d_in[7];
    const float* sw3 = (const float*)d_in[8];  const float* sb3 = (const float*)d_in[9];
    const float* gw0 = (const float*)d_in[10]; const float* gb0 = (const float*)d_in[11];
    const float* gw1 = (const float*)d_in[12]; const float* gb1 = (const float*)d_in[13];
    const float* fw0 = (const float*)d_in[14]; const float* fb0 = (const float*)d_in[15];
    const float* fw1 = (const float*)d_in[16]; const float* fb1 = (const float*)d_in[17];
    const float* fw2 = (const float*)d_in[18]; const float* fb2 = (const float*)d_in[19];
    const float* lw0 = (const float*)d_in[20]; const float* lb0 = (const float*)d_in[21];
    const float* lw1 = (const float*)d_in[22];
    const float* pw  = (const float*)d_in[23]; const float* pb  = (const float*)d_in[24];
    const float* ccm_w  = (const float*)d_in[25]; const float* ccm_b = (const float*)d_in[26];
    const float* shifts = (const float*)d_in[27];
    const float* slopes = (const float*)d_in[28];
    const float* proj_w = (const float*)d_in[29];
    const float* proj_b = (const float*)d_in[30];
    float* out = (float*)d_out;

    const int B = in_sizes[0] / (3 * 256 * 256);   // = 2

    // workspace carve (floats)
    float* ws = (float*)d_ws;
    float* x0   = ws;                                // B*8*128*128   CHW
    float* x1   = x0 + (size_t)B * 8  * 128 * 128;   // B*16*64*64    CHW
    float* x2   = x1 + (size_t)B * 16 * 64 * 64;     // B*32*32*32    HWC
    float* x3   = x2 + (size_t)B * 32 * 32 * 32;     // B*16*16*64    HWC
    float* g0   = x3 + (size_t)B * 64 * 16 * 16;     // B*8*8*64      HWC
    float* g1   = g0 + (size_t)B * 64 * 8 * 8;       // B*64*4*4      CHW
    float* f0   = g1 + (size_t)B * 64 * 4 * 4;       // B*256
    float* loc0 = f0 + (size_t)B * 256;              // B*16*16*64    HWC
    float* loc1 = loc0 + (size_t)B * 64 * 16 * 16;   // B*16*16*64    HWC
    float* sco  = loc1 + (size_t)B * 64 * 16 * 16;   // B*256*96

    const int T = 256;

    // 1-3: splat chain (wide)
    conv3x3_chw_k<<<cdiv(B * 8 * 128 * 128, T), T, 0, stream>>>(img_lo, sw0, sb0, x0, B, 3, 256, 256, 8, 128, 128, 2);
    conv3x3_chw_k<<<cdiv(B * 16 * 64 * 64, T), T, 0, stream>>>(x0, sw1, sb1, x1, B, 8, 128, 128, 16, 64, 64, 2);
    conv3x3_hwc_k<<<cdiv(B * 32 * 32 * 32, T), T, 0, stream>>>(x1, sw2, sb2, x2, B, 16, 64, 64, 32, 32, 32, 2);
    // 4: conv3 (wave)
    conv3_k<<<cdiv(B * 32 * 16 * 16 * 64, T), T, 0, stream>>>(x2, sw3, sb3, x3, B);
    // 5: gconv0 || lconv0
    {
        int nwaves = B * 64 * 8 * 8 + B * 64 * 16 * 16;
        gl0_k<<<cdiv(nwaves * 64, T), T, 0, stream>>>(x3, gw0, gb0, g0, lw0, lb0, loc0, B);
    }
    // 6: gconv1 || lconv1
    {
        int nwaves = B * 64 * 4 * 4 + B * 64 * 16 * 16;
        gl1_k<<<cdiv(nwaves * 64, T), T, 0, stream>>>(g0, loc0, gw1, gb1, g1, lw1, loc1, B);
    }
    // 7: fc0 (wide, wave per output)
    fc0_k<<<cdiv(B * 256 * 64, T), T, 0, stream>>>(g1, fw0, fb0, f0, B);
    // 8: fc1+fc2+pred -> sco
    pred_k<<<B * 32, 256, 0, stream>>>(f0, fw1, fb1, fw2, fb2, loc1, pw, pb, sco);
    // 9: guide + slice + apply (32x32-px tiles, 2x2-cell LDS footprint)
    apply_k<<<B * 1024, 256, 0, stream>>>(img_fr, sco, ccm_w, ccm_b, shifts, slopes,
                                          proj_w, proj_b, out);
}

// Round 9
// 164.046 us; speedup vs baseline: 1.3700x; 1.3700x over previous
//
#include <hip/hip_runtime.h>
#include <math.h>

// ---------------------------------------------------------------------------
// DeepBilateralNetCurves (HDRNet) forward, f32.
// B=2, lowres 3x256x256, fullres 3x1024x1024, grid 12x8x16x16, 16-pt curve.
//
// Round 8 post-mortem: apply_k kept curve params in LDS (96 uniform
// ds_read_b32 per pixel!) and ran at 176 VGPR / 2 waves per SIMD. Round 9:
// uniform params read from global (compiler hoists to SGPRs), 4px/thread
// float4 I/O, coeffs folded into 3 accumulators, __launch_bounds__(256,4).
// 9 launches: conv0..conv3, gl0, gl1, fc0, pred, apply.
// ---------------------------------------------------------------------------

static inline int cdiv(int a, int b) { return (a + b - 1) / b; }

// ---- wide naive 3x3 convs (small Cin) --------------------------------------

__global__ void conv3x3_chw_k(const float* __restrict__ in, const float* __restrict__ wgt,
                              const float* __restrict__ bias, float* __restrict__ out,
                              int B, int Cin, int Hin, int Win,
                              int Cout, int Hout, int Wout, int stride) {
    int total = B * Cout * Hout * Wout;
    int idx = blockIdx.x * blockDim.x + threadIdx.x;
    if (idx >= total) return;
    int wo = idx % Wout;
    int ho = (idx / Wout) % Hout;
    int co = (idx / (Wout * Hout)) % Cout;
    int b  = idx / (Wout * Hout * Cout);
    float acc = bias[co];
    int hb = ho * stride - 1, wb = wo * stride - 1;
    const float* wr = wgt + (size_t)co * Cin * 9;
    const float* ib = in + (size_t)b * Cin * Hin * Win;
    for (int ci = 0; ci < Cin; ++ci) {
        const float* ip = ib + (size_t)ci * Hin * Win;
        const float* wp = wr + ci * 9;
#pragma unroll
        for (int ky = 0; ky < 3; ++ky) {
            int hi = hb + ky;
            if (hi < 0 || hi >= Hin) continue;
#pragma unroll
            for (int kx = 0; kx < 3; ++kx) {
                int wi = wb + kx;
                if (wi < 0 || wi >= Win) continue;
                acc += ip[hi * Win + wi] * wp[ky * 3 + kx];
            }
        }
    }
    out[idx] = fmaxf(acc, 0.0f);
}

__global__ void conv3x3_hwc_k(const float* __restrict__ in, const float* __restrict__ wgt,
                              const float* __restrict__ bias, float* __restrict__ out,
                              int B, int Cin, int Hin, int Win,
                              int Cout, int Hout, int Wout, int stride) {
    int total = B * Cout * Hout * Wout;
    int idx = blockIdx.x * blockDim.x + threadIdx.x;
    if (idx >= total) return;
    int co = idx % Cout;
    int wo = (idx / Cout) % Wout;
    int ho = (idx / (Cout * Wout)) % Hout;
    int b  = idx / (Cout * Wout * Hout);
    float acc = bias[co];
    int hb = ho * stride - 1, wb = wo * stride - 1;
    const float* wr = wgt + (size_t)co * Cin * 9;
    const float* ib = in + (size_t)b * Cin * Hin * Win;
    for (int ci = 0; ci < Cin; ++ci) {
        const float* ip = ib + (size_t)ci * Hin * Win;
        const float* wp = wr + ci * 9;
#pragma unroll
        for (int ky = 0; ky < 3; ++ky) {
            int hi = hb + ky;
            if (hi < 0 || hi >= Hin) continue;
#pragma unroll
            for (int kx = 0; kx < 3; ++kx) {
                int wi = wb + kx;
                if (wi < 0 || wi >= Win) continue;
                acc += ip[hi * Win + wi] * wp[ky * 3 + kx];
            }
        }
    }
    out[idx] = fmaxf(acc, 0.0f);  // idx == HWC flat index
}

// ---- wave-per-output conv (HWC input, lane = ci) ---------------------------

__device__ __forceinline__ void wave_conv_one(
    const float* __restrict__ in, const float* __restrict__ wgt,
    const float* __restrict__ bias, float* __restrict__ out,
    int B, int Cin, int Hin, int Win, int Cout, int Hout, int Wout,
    int stride, int relu, int out_chw, int wid, int lane) {
    int copw = (Cin == 64) ? 1 : 2;
    int cow  = Cout / copw;
    int ci   = lane & (Cin - 1);
    int cw = wid % cow;
    int wo = (wid / cow) % Wout;
    int ho = (wid / (cow * Wout)) % Hout;
    int b  = wid / (cow * Wout * Hout);
    int co = cw * copw + ((copw == 2) ? (lane >> 5) : 0);
    int hb = ho * stride - 1, wb = wo * stride - 1;
    const float* wp = wgt + ((size_t)co * Cin + ci) * 9;
    float acc = 0.0f;
#pragma unroll
    for (int ky = 0; ky < 3; ++ky) {
        int hi = hb + ky;
        if (hi < 0 || hi >= Hin) continue;
#pragma unroll
        for (int kx = 0; kx < 3; ++kx) {
            int wi = wb + kx;
            if (wi < 0 || wi >= Win) continue;
            acc += in[((size_t)(b * Hin + hi) * Win + wi) * Cin + ci] * wp[ky * 3 + kx];
        }
    }
    for (int m = 1; m < Cin; m <<= 1) acc += __shfl_xor(acc, m);
    if (ci == 0) {
        if (bias) acc += bias[co];
        if (relu) acc = fmaxf(acc, 0.0f);
        if (out_chw) out[((size_t)(b * Cout + co) * Hout + ho) * Wout + wo] = acc;
        else         out[((size_t)(b * Hout + ho) * Wout + wo) * Cout + co] = acc;
    }
}

// conv3: 32->64, 32x32 -> 16x16, stride 2, HWC->HWC
__global__ void conv3_k(const float* __restrict__ x2, const float* __restrict__ w,
                        const float* __restrict__ bias, float* __restrict__ x3, int B) {
    int tid = blockIdx.x * blockDim.x + threadIdx.x;
    int wid = tid >> 6, lane = threadIdx.x & 63;
    int nw = B * 32 * 16 * 16;
    if (wid >= nw) return;
    wave_conv_one(x2, w, bias, x3, B, 32, 32, 32, 64, 16, 16, 2, 1, 0, wid, lane);
}

// gconv0 (64ch 16->8, s2) || lconv0 (64ch 16x16, s1, relu)
__global__ void gl0_k(const float* __restrict__ x3,
                      const float* __restrict__ gw, const float* __restrict__ gb, float* __restrict__ g0,
                      const float* __restrict__ lw, const float* __restrict__ lb, float* __restrict__ loc0,
                      int B) {
    int tid = blockIdx.x * blockDim.x + threadIdx.x;
    int wid = tid >> 6, lane = threadIdx.x & 63;
    int ng = B * 64 * 8 * 8;
    int nl = B * 64 * 16 * 16;
    if (wid < ng)            wave_conv_one(x3, gw, gb, g0,  B, 64, 16, 16, 64, 8, 8,  2, 1, 0, wid, lane);
    else if (wid < ng + nl)  wave_conv_one(x3, lw, lb, loc0, B, 64, 16, 16, 64, 16, 16, 1, 1, 0, wid - ng, lane);
}

// gconv1 (64ch 8->4, s2, CHW out for FC flatten) || lconv1 (no relu)
__global__ void gl1_k(const float* __restrict__ g0, const float* __restrict__ loc0,
                      const float* __restrict__ gw, const float* __restrict__ gb, float* __restrict__ g1,
                      const float* __restrict__ lw, float* __restrict__ loc1, int B) {
    int tid = blockIdx.x * blockDim.x + threadIdx.x;
    int wid = tid >> 6, lane = threadIdx.x & 63;
    int ng = B * 64 * 4 * 4;
    int nl = B * 64 * 16 * 16;
    if (wid < ng)            wave_conv_one(g0, gw, gb, g1,   B, 64, 8, 8,  64, 4, 4,  2, 1, 1, wid, lane);
    else if (wid < ng + nl)  wave_conv_one(loc0, lw, nullptr, loc1, B, 64, 16, 16, 64, 16, 16, 1, 0, 0, wid - ng, lane);
}

// fc0: wave per (b,o), 1024-dot, relu. out f0[b*256+o].
__global__ void fc0_k(const float* __restrict__ g1, const float* __restrict__ fw0,
                      const float* __restrict__ fb0, float* __restrict__ f0, int B) {
    int tid  = blockIdx.x * blockDim.x + threadIdx.x;
    int wid  = tid >> 6;
    int lane = threadIdx.x & 63;
    if (wid >= B * 256) return;
    int o = wid & 255, b = wid >> 8;
    const float* ip = g1 + (size_t)b * 1024;
    const float* wp = fw0 + (size_t)o * 1024;
    float acc = 0.0f;
    for (int j = lane; j < 1024; j += 64) acc += ip[j] * wp[j];
    for (int m = 1; m < 64; m <<= 1) acc += __shfl_xor(acc, m);
    if (lane == 0) f0[wid] = fmaxf(acc + fb0[o], 0.0f);
}

// ---- pred_k: fc1 + fc2 (per-block redundant) + grid coeffs -> sco ----------
// grid = B*32 blocks x 256 thr; each block computes 8 cells x 96 channels.
// sco layout: sco[b*24576 + cell*96 + z*12 + c], cell = y*16+x.
__global__ __launch_bounds__(256) void pred_k(
    const float* __restrict__ f0g,
    const float* __restrict__ fw1, const float* __restrict__ fb1,
    const float* __restrict__ fw2, const float* __restrict__ fb2,
    const float* __restrict__ loc1,
    const float* __restrict__ pw, const float* __restrict__ pb,
    float* __restrict__ sco) {
    __shared__ float s_pw[96 * 65];
    __shared__ float s_pb[96];
    __shared__ float s_f0[256];
    __shared__ float s_f1[128];
    __shared__ float s_f2[64];
    __shared__ __align__(16) float s_loc[8 * 64];

    const int t    = threadIdx.x;
    const int b    = blockIdx.x >> 5;
    const int part = blockIdx.x & 31;       // 8 cells per part
    const int wl   = t >> 6;
    const int lane = t & 63;

    // stage pw (padded rows), pb, f0, loc1 cells
    {
        const float4* pw4 = (const float4*)pw;  // 1536 float4
        for (int j = t; j < 1536; j += 256) {
            float4 v = pw4[j];
            int base = j * 4;
            int c = base >> 6, i = base & 63;
            float* dst = &s_pw[c * 65 + i];
            dst[0] = v.x; dst[1] = v.y; dst[2] = v.z; dst[3] = v.w;
        }
        s_f0[t] = f0g[b * 256 + t];
        if (t < 96) s_pb[t] = pb[t];
        if (t < 128) {  // 8 cells x 64 ch = 128 float4
            int cell = t >> 4, i4 = t & 15;
            float4 v = ((const float4*)(loc1 + ((size_t)(b * 256 + part * 8 + cell)) * 64))[i4];
            ((float4*)(s_loc + cell * 64))[i4] = v;
        }
    }
    __syncthreads();

    // fc1: 128 outputs, wave-dots over s_f0 (weights L2-hot)
    for (int o = wl; o < 128; o += 4) {
        const float* wp = fw1 + (size_t)o * 256;
        float acc = 0.0f;
#pragma unroll
        for (int j = lane; j < 256; j += 64) acc += s_f0[j] * wp[j];
        for (int m = 1; m < 64; m <<= 1) acc += __shfl_xor(acc, m);
        if (lane == 0) s_f1[o] = fmaxf(acc + fb1[o], 0.0f);
    }
    __syncthreads();
    // fc2: 64 outputs (no relu)
    for (int o = wl; o < 64; o += 4) {
        const float* wp = fw2 + (size_t)o * 128;
        float acc = 0.0f;
#pragma unroll
        for (int j = lane; j < 128; j += 64) acc += s_f1[j] * wp[j];
        for (int m = 1; m < 64; m <<= 1) acc += __shfl_xor(acc, m);
        if (lane == 0) s_f2[o] = acc + fb2[o];
    }
    __syncthreads();

    // pred: 768 outputs per block, 3 per thread
#pragma unroll
    for (int k = 0; k < 3; ++k) {
        int v = k * 256 + t;            // 0..767
        int lcell = v / 96;             // 0..7
        int c = v % 96;
        const float* wp = &s_pw[c * 65];
        const float* lp = &s_loc[lcell * 64];
        float acc = s_pb[c];
        for (int i = 0; i < 64; ++i)
            acc += wp[i] * fmaxf(s_f2[i] + lp[i], 0.0f);
        sco[(size_t)b * 24576 + part * 768 + v] = acc;
    }
}

// ---- apply_k: guide + trilinear slice + affine apply -----------------------
// One block per 32x32-px tile (grid = B*1024); 4 px per thread via float4.
// A 32x32 tile has constant (fy,fx) -> footprint = 2x2 cells in 1.5KB LDS.
// Wave-uniform params (curve/ccm/proj) are read from GLOBAL with uniform
// indices -> compiler hoists to SGPR s_loads (NOT LDS: per-px ds_reads of
// uniform values were the round-8 bottleneck).
__global__ __launch_bounds__(256, 4) void apply_k(
    const float* __restrict__ img, const float* __restrict__ sco,
    const float* __restrict__ ccm_w, const float* __restrict__ ccm_b,
    const float* __restrict__ shifts, const float* __restrict__ slopes,
    const float* __restrict__ proj_w, const float* __restrict__ proj_b,
    float* __restrict__ out) {
    __shared__ __align__(16) float s_sco[4 * 96];   // 2x2 cells x (z*12+c)

    const int t   = threadIdx.x;
    const int b   = blockIdx.x >> 10;
    const int rem = blockIdx.x & 1023;
    const int ty  = rem >> 5;           // 32-px tile row
    const int tx  = rem & 31;           // 32-px tile col
    const int fy0 = (ty - 1) >> 1;      // constant floor(ys) over tile
    const int fx0 = (tx - 1) >> 1;

    // stage 2x2 cells (4 x 96 floats = 96 float4)
    if (t < 96) {
        int cell = t / 24;
        int i4 = t % 24;
        int dy = cell >> 1, dx = cell & 1;
        int gy = min(max(fy0 + dy, 0), 15);
        int gx = min(max(fx0 + dx, 0), 15);
        float4 v = ((const float4*)(sco + ((size_t)b * 256 + gy * 16 + gx) * 96))[i4];
        ((float4*)(s_sco + cell * 96))[i4] = v;
    }
    __syncthreads();

    const size_t plane = 1024 * 1024;
    const float* ibase = img + (size_t)b * 3 * plane;
    float* obase = out + (size_t)b * 3 * plane;

    const int row = t >> 3;                  // 0..31
    const int xg  = (t & 7) * 4;             // 0,4,...,28
    const int y = ty * 32 + row;
    const int x0 = tx * 32 + xg;
    const size_t off = (size_t)y * 1024 + x0;

    float4 r4 = *(const float4*)(ibase + off);
    float4 g4 = *(const float4*)(ibase + plane + off);
    float4 b4 = *(const float4*)(ibase + 2 * plane + off);
    const float rj[4] = { r4.x, r4.y, r4.z, r4.w };
    const float gj[4] = { g4.x, g4.y, g4.z, g4.w };
    const float bj[4] = { b4.x, b4.y, b4.z, b4.w };

    // y-weights shared by all 4 px (same row)
    float ys = ((float)y + 0.5f) * 0.015625f - 0.5f;
    float wy1 = ys - (float)fy0;            // weight for dy=1 (1-|ys-(fy0+1)|)
    float wy0 = 1.0f - wy1;

    float o_r[4], o_g[4], o_b[4];

#pragma unroll
    for (int j = 0; j < 4; ++j) {
        float r = rj[j], g = gj[j], bl = bj[j];

        // ---- guide (params -> SGPRs via uniform global loads) ----
        float gd = proj_b[0];
#pragma unroll
        for (int c = 0; c < 3; ++c) {
            float v = ccm_b[c] + ccm_w[c * 3 + 0] * r + ccm_w[c * 3 + 1] * g + ccm_w[c * 3 + 2] * bl;
            float acc = 0.0f;
#pragma unroll
            for (int p = 0; p < 16; ++p)
                acc += slopes[c * 16 + p] * fmaxf(v - shifts[c * 16 + p], 0.0f);
            gd += proj_w[c] * acc;
        }
        gd = fminf(fmaxf(gd, 0.0f), 1.0f);

        // ---- slice weights ----
        float xs = ((float)(x0 + j) + 0.5f) * 0.015625f - 0.5f;
        float wx1 = xs - (float)fx0;
        float wx0 = 1.0f - wx1;
        float gz = gd * 8.0f - 0.5f;
        float fzf = floorf(gz);
        int fz = (int)fzf;
        float wz1 = gz - fzf;
        float wz0 = 1.0f - wz1;

        float ar = 0.0f, ag = 0.0f, ab = 0.0f;
#pragma unroll
        for (int dz = 0; dz < 2; ++dz) {
            int zi = min(max(fz + dz, 0), 7);
            float wz = dz ? wz1 : wz0;
#pragma unroll
            for (int dy = 0; dy < 2; ++dy) {
                float wzy = wz * (dy ? wy1 : wy0);
#pragma unroll
                for (int dx = 0; dx < 2; ++dx) {
                    float wt = wzy * (dx ? wx1 : wx0);
                    const float4* gp = (const float4*)(s_sco + ((dy * 2 + dx) * 96 + zi * 12));
                    float4 a0 = gp[0], a1 = gp[1], a2 = gp[2];
                    ar += wt * (a0.x * r + a0.y * g + a0.z * bl + a0.w);
                    ag += wt * (a1.x * r + a1.y * g + a1.z * bl + a1.w);
                    ab += wt * (a2.x * r + a2.y * g + a2.z * bl + a2.w);
                }
            }
        }
        o_r[j] = fminf(fmaxf(ar, 0.0f), 1.0f);
        o_g[j] = fminf(fmaxf(ag, 0.0f), 1.0f);
        o_b[j] = fminf(fmaxf(ab, 0.0f), 1.0f);
    }

    *(float4*)(obase + off)             = make_float4(o_r[0], o_r[1], o_r[2], o_r[3]);
    *(float4*)(obase + plane + off)     = make_float4(o_g[0], o_g[1], o_g[2], o_g[3]);
    *(float4*)(obase + 2 * plane + off) = make_float4(o_b[0], o_b[1], o_b[2], o_b[3]);
}

// ---------------------------------------------------------------------------

extern "C" void kernel_launch(void* const* d_in, const int* in_sizes, int n_in,
                              void* d_out, int out_size, void* d_ws, size_t ws_size,
                              hipStream_t stream) {
    const float* img_lo = (const float*)d_in[0];
    const float* img_fr = (const float*)d_in[1];
    const float* sw0 = (const float*)d_in[2];  const float* sb0 = (const float*)d_in[3];
    const float* sw1 = (const float*)d_in[4];  const float* sb1 = (const float*)d_in[5];
    const float* sw2 = (const float*)d_in[6];  const float* sb2 = (const float*)d_in[7];
    const float* sw3 = (const float*)d_in[8];  const float* sb3 = (const float*)d_in[9];
    const float* gw0 = (const float*)d_in[10]; const float* gb0 = (const float*)d_in[11];
    const float* gw1 = (const float*)d_in[12]; const float* gb1 = (const float*)d_in[13];
    const float* fw0 = (const float*)d_in[14]; const float* fb0 = (const float*)d_in[15];
    const float* fw1 = (const float*)d_in[16]; const float* fb1 = (const float*)d_in[17];
    const float* fw2 = (const float*)d_in[18]; const float* fb2 = (const float*)d_in[19];
    const float* lw0 = (const float*)d_in[20]; const float* lb0 = (const float*)d_in[21];
    const float* lw1 = (const float*)d_in[22];
    const float* pw  = (const float*)d_in[23]; const float* pb  = (const float*)d_in[24];
    const float* ccm_w  = (const float*)d_in[25]; const float* ccm_b = (const float*)d_in[26];
    const float* shifts = (const float*)d_in[27];
    const float* slopes = (const float*)d_in[28];
    const float* proj_w = (const float*)d_in[29];
    const float* proj_b = (const float*)d_in[30];
    float* out = (float*)d_out;

    const int B = in_sizes[0] / (3 * 256 * 256);   // = 2

    // workspace carve (floats)
    float* ws = (float*)d_ws;
    float* x0   = ws;                                // B*8*128*128   CHW
    float* x1   = x0 + (size_t)B * 8  * 128 * 128;   // B*16*64*64    CHW
    float* x2   = x1 + (size_t)B * 16 * 64 * 64;     // B*32*32*32    HWC
    float* x3   = x2 + (size_t)B * 32 * 32 * 32;     // B*16*16*64    HWC
    float* g0   = x3 + (size_t)B * 64 * 16 * 16;     // B*8*8*64      HWC
    float* g1   = g0 + (size_t)B * 64 * 8 * 8;       // B*64*4*4      CHW
    float* f0   = g1 + (size_t)B * 64 * 4 * 4;       // B*256
    float* loc0 = f0 + (size_t)B * 256;              // B*16*16*64    HWC
    float* loc1 = loc0 + (size_t)B * 64 * 16 * 16;   // B*16*16*64    HWC
    float* sco  = loc1 + (size_t)B * 64 * 16 * 16;   // B*256*96

    const int T = 256;

    // 1-3: splat chain (wide)
    conv3x3_chw_k<<<cdiv(B * 8 * 128 * 128, T), T, 0, stream>>>(img_lo, sw0, sb0, x0, B, 3, 256, 256, 8, 128, 128, 2);
    conv3x3_chw_k<<<cdiv(B * 16 * 64 * 64, T), T, 0, stream>>>(x0, sw1, sb1, x1, B, 8, 128, 128, 16, 64, 64, 2);
    conv3x3_hwc_k<<<cdiv(B * 32 * 32 * 32, T), T, 0, stream>>>(x1, sw2, sb2, x2, B, 16, 64, 64, 32, 32, 32, 2);
    // 4: conv3 (wave)
    conv3_k<<<cdiv(B * 32 * 16 * 16 * 64, T), T, 0, stream>>>(x2, sw3, sb3, x3, B);
    // 5: gconv0 || lconv0
    {
        int nwaves = B * 64 * 8 * 8 + B * 64 * 16 * 16;
        gl0_k<<<cdiv(nwaves * 64, T), T, 0, stream>>>(x3, gw0, gb0, g0, lw0, lb0, loc0, B);
    }
    // 6: gconv1 || lconv1
    {
        int nwaves = B * 64 * 4 * 4 + B * 64 * 16 * 16;
        gl1_k<<<cdiv(nwaves * 64, T), T, 0, stream>>>(g0, loc0, gw1, gb1, g1, lw1, loc1, B);
    }
    // 7: fc0 (wide, wave per output)
    fc0_k<<<cdiv(B * 256 * 64, T), T, 0, stream>>>(g1, fw0, fb0, f0, B);
    // 8: fc1+fc2+pred -> sco
    pred_k<<<B * 32, 256, 0, stream>>>(f0, fw1, fb1, fw2, fb2, loc1, pw, pb, sco);
    // 9: guide + slice + apply (32x32-px tiles, 4px/thread float4)
    apply_k<<<B * 1024, 256, 0, stream>>>(img_fr, sco, ccm_w, ccm_b, shifts, slopes,
                                          proj_w, proj_b, out);
}

// Round 10
// 153.146 us; speedup vs baseline: 1.4676x; 1.0712x over previous
//
#include <hip/hip_runtime.h>
#include <math.h>

// ---------------------------------------------------------------------------
// DeepBilateralNetCurves (HDRNet) forward, f32.
// B=2, lowres 3x256x256, fullres 3x1024x1024, grid 12x8x16x16, 16-pt curve.
//
// Round 9 post-mortem: pred_k was latency-bound (64 blocks, 1 wave/SIMD,
// serial L2-latency fc dots): 41us @ 2.45% occupancy. apply_k's px loop is
// LDS-issue bound (24 ds_read_b128/px).
// Round 10:
//  - pred_k v2: B*256 blocks x 512 thr; fc1/fc2 redundant across 8 waves;
//    pred = wave-per-output with hoisted act[lane], no pw staging.
//  - apply_k v2: y-interp pre-reduced into LDS R[row][dx][z][12] (built once
//    per block) -> 12 b128/px instead of 24; padded row stride.
// 9 launches: conv0..conv3, gl0, gl1, fc0, pred, apply.
// ---------------------------------------------------------------------------

static inline int cdiv(int a, int b) { return (a + b - 1) / b; }

// ---- wide naive 3x3 convs (small Cin) --------------------------------------

__global__ void conv3x3_chw_k(const float* __restrict__ in, const float* __restrict__ wgt,
                              const float* __restrict__ bias, float* __restrict__ out,
                              int B, int Cin, int Hin, int Win,
                              int Cout, int Hout, int Wout, int stride) {
    int total = B * Cout * Hout * Wout;
    int idx = blockIdx.x * blockDim.x + threadIdx.x;
    if (idx >= total) return;
    int wo = idx % Wout;
    int ho = (idx / Wout) % Hout;
    int co = (idx / (Wout * Hout)) % Cout;
    int b  = idx / (Wout * Hout * Cout);
    float acc = bias[co];
    int hb = ho * stride - 1, wb = wo * stride - 1;
    const float* wr = wgt + (size_t)co * Cin * 9;
    const float* ib = in + (size_t)b * Cin * Hin * Win;
    for (int ci = 0; ci < Cin; ++ci) {
        const float* ip = ib + (size_t)ci * Hin * Win;
        const float* wp = wr + ci * 9;
#pragma unroll
        for (int ky = 0; ky < 3; ++ky) {
            int hi = hb + ky;
            if (hi < 0 || hi >= Hin) continue;
#pragma unroll
            for (int kx = 0; kx < 3; ++kx) {
                int wi = wb + kx;
                if (wi < 0 || wi >= Win) continue;
                acc += ip[hi * Win + wi] * wp[ky * 3 + kx];
            }
        }
    }
    out[idx] = fmaxf(acc, 0.0f);
}

__global__ void conv3x3_hwc_k(const float* __restrict__ in, const float* __restrict__ wgt,
                              const float* __restrict__ bias, float* __restrict__ out,
                              int B, int Cin, int Hin, int Win,
                              int Cout, int Hout, int Wout, int stride) {
    int total = B * Cout * Hout * Wout;
    int idx = blockIdx.x * blockDim.x + threadIdx.x;
    if (idx >= total) return;
    int co = idx % Cout;
    int wo = (idx / Cout) % Wout;
    int ho = (idx / (Cout * Wout)) % Hout;
    int b  = idx / (Cout * Wout * Hout);
    float acc = bias[co];
    int hb = ho * stride - 1, wb = wo * stride - 1;
    const float* wr = wgt + (size_t)co * Cin * 9;
    const float* ib = in + (size_t)b * Cin * Hin * Win;
    for (int ci = 0; ci < Cin; ++ci) {
        const float* ip = ib + (size_t)ci * Hin * Win;
        const float* wp = wr + ci * 9;
#pragma unroll
        for (int ky = 0; ky < 3; ++ky) {
            int hi = hb + ky;
            if (hi < 0 || hi >= Hin) continue;
#pragma unroll
            for (int kx = 0; kx < 3; ++kx) {
                int wi = wb + kx;
                if (wi < 0 || wi >= Win) continue;
                acc += ip[hi * Win + wi] * wp[ky * 3 + kx];
            }
        }
    }
    out[idx] = fmaxf(acc, 0.0f);  // idx == HWC flat index
}

// ---- wave-per-output conv (HWC input, lane = ci) ---------------------------

__device__ __forceinline__ void wave_conv_one(
    const float* __restrict__ in, const float* __restrict__ wgt,
    const float* __restrict__ bias, float* __restrict__ out,
    int B, int Cin, int Hin, int Win, int Cout, int Hout, int Wout,
    int stride, int relu, int out_chw, int wid, int lane) {
    int copw = (Cin == 64) ? 1 : 2;
    int cow  = Cout / copw;
    int ci   = lane & (Cin - 1);
    int cw = wid % cow;
    int wo = (wid / cow) % Wout;
    int ho = (wid / (cow * Wout)) % Hout;
    int b  = wid / (cow * Wout * Hout);
    int co = cw * copw + ((copw == 2) ? (lane >> 5) : 0);
    int hb = ho * stride - 1, wb = wo * stride - 1;
    const float* wp = wgt + ((size_t)co * Cin + ci) * 9;
    float acc = 0.0f;
#pragma unroll
    for (int ky = 0; ky < 3; ++ky) {
        int hi = hb + ky;
        if (hi < 0 || hi >= Hin) continue;
#pragma unroll
        for (int kx = 0; kx < 3; ++kx) {
            int wi = wb + kx;
            if (wi < 0 || wi >= Win) continue;
            acc += in[((size_t)(b * Hin + hi) * Win + wi) * Cin + ci] * wp[ky * 3 + kx];
        }
    }
    for (int m = 1; m < Cin; m <<= 1) acc += __shfl_xor(acc, m);
    if (ci == 0) {
        if (bias) acc += bias[co];
        if (relu) acc = fmaxf(acc, 0.0f);
        if (out_chw) out[((size_t)(b * Cout + co) * Hout + ho) * Wout + wo] = acc;
        else         out[((size_t)(b * Hout + ho) * Wout + wo) * Cout + co] = acc;
    }
}

// conv3: 32->64, 32x32 -> 16x16, stride 2, HWC->HWC
__global__ void conv3_k(const float* __restrict__ x2, const float* __restrict__ w,
                        const float* __restrict__ bias, float* __restrict__ x3, int B) {
    int tid = blockIdx.x * blockDim.x + threadIdx.x;
    int wid = tid >> 6, lane = threadIdx.x & 63;
    int nw = B * 32 * 16 * 16;
    if (wid >= nw) return;
    wave_conv_one(x2, w, bias, x3, B, 32, 32, 32, 64, 16, 16, 2, 1, 0, wid, lane);
}

// gconv0 (64ch 16->8, s2) || lconv0 (64ch 16x16, s1, relu)
__global__ void gl0_k(const float* __restrict__ x3,
                      const float* __restrict__ gw, const float* __restrict__ gb, float* __restrict__ g0,
                      const float* __restrict__ lw, const float* __restrict__ lb, float* __restrict__ loc0,
                      int B) {
    int tid = blockIdx.x * blockDim.x + threadIdx.x;
    int wid = tid >> 6, lane = threadIdx.x & 63;
    int ng = B * 64 * 8 * 8;
    int nl = B * 64 * 16 * 16;
    if (wid < ng)            wave_conv_one(x3, gw, gb, g0,  B, 64, 16, 16, 64, 8, 8,  2, 1, 0, wid, lane);
    else if (wid < ng + nl)  wave_conv_one(x3, lw, lb, loc0, B, 64, 16, 16, 64, 16, 16, 1, 1, 0, wid - ng, lane);
}

// gconv1 (64ch 8->4, s2, CHW out for FC flatten) || lconv1 (no relu)
__global__ void gl1_k(const float* __restrict__ g0, const float* __restrict__ loc0,
                      const float* __restrict__ gw, const float* __restrict__ gb, float* __restrict__ g1,
                      const float* __restrict__ lw, float* __restrict__ loc1, int B) {
    int tid = blockIdx.x * blockDim.x + threadIdx.x;
    int wid = tid >> 6, lane = threadIdx.x & 63;
    int ng = B * 64 * 4 * 4;
    int nl = B * 64 * 16 * 16;
    if (wid < ng)            wave_conv_one(g0, gw, gb, g1,   B, 64, 8, 8,  64, 4, 4,  2, 1, 1, wid, lane);
    else if (wid < ng + nl)  wave_conv_one(loc0, lw, nullptr, loc1, B, 64, 16, 16, 64, 16, 16, 1, 0, 0, wid - ng, lane);
}

// fc0: wave per (b,o), 1024-dot, relu. out f0[b*256+o].
__global__ void fc0_k(const float* __restrict__ g1, const float* __restrict__ fw0,
                      const float* __restrict__ fb0, float* __restrict__ f0, int B) {
    int tid  = blockIdx.x * blockDim.x + threadIdx.x;
    int wid  = tid >> 6;
    int lane = threadIdx.x & 63;
    if (wid >= B * 256) return;
    int o = wid & 255, b = wid >> 8;
    const float* ip = g1 + (size_t)b * 1024;
    const float* wp = fw0 + (size_t)o * 1024;
    float acc = 0.0f;
    for (int j = lane; j < 1024; j += 64) acc += ip[j] * wp[j];
    for (int m = 1; m < 64; m <<= 1) acc += __shfl_xor(acc, m);
    if (lane == 0) f0[wid] = fmaxf(acc + fb0[o], 0.0f);
}

// ---- pred_k v2: one cell per block, 8 waves --------------------------------
// fc1/fc2 computed redundantly per block (weights L2-hot, spread over waves);
// pred is wave-per-output: act[lane] hoisted, 12 dots/wave of {coalesced pw
// load + butterfly reduce}. sco[b*24576 + cell*96 + z*12 + c].
__global__ __launch_bounds__(512) void pred_k(
    const float* __restrict__ f0g,
    const float* __restrict__ fw1, const float* __restrict__ fb1,
    const float* __restrict__ fw2, const float* __restrict__ fb2,
    const float* __restrict__ loc1,
    const float* __restrict__ pw, const float* __restrict__ pb,
    float* __restrict__ sco) {
    __shared__ float s_f0[256];
    __shared__ float s_f1[128];
    __shared__ float s_f2[64];
    __shared__ float s_loc[64];

    const int t    = threadIdx.x;
    const int b    = blockIdx.x >> 8;
    const int cell = blockIdx.x & 255;
    const int wl   = t >> 6;            // 0..7
    const int lane = t & 63;

    if (t < 256) s_f0[t] = f0g[b * 256 + t];
    else if (t < 320) s_loc[t - 256] = loc1[((size_t)(b * 256 + cell)) * 64 + (t - 256)];
    __syncthreads();

    // fc1: 128 outputs over 8 waves (16 dots/wave, len-256, 4 loads/lane)
    for (int o = wl; o < 128; o += 8) {
        const float* wp = fw1 + (size_t)o * 256;
        float acc = 0.0f;
#pragma unroll
        for (int j = 0; j < 4; ++j) acc += s_f0[lane + j * 64] * wp[lane + j * 64];
        for (int m = 1; m < 64; m <<= 1) acc += __shfl_xor(acc, m);
        if (lane == 0) s_f1[o] = fmaxf(acc + fb1[o], 0.0f);
    }
    __syncthreads();
    // fc2: 64 outputs over 8 waves (8 dots/wave, len-128)
    for (int o = wl; o < 64; o += 8) {
        const float* wp = fw2 + (size_t)o * 128;
        float acc = s_f1[lane] * wp[lane] + s_f1[lane + 64] * wp[lane + 64];
        for (int m = 1; m < 64; m <<= 1) acc += __shfl_xor(acc, m);
        if (lane == 0) s_f2[o] = acc + fb2[o];
    }
    __syncthreads();

    // pred: act hoisted, 96 outputs over 8 waves (12 dots/wave)
    float act = fmaxf(s_f2[lane] + s_loc[lane], 0.0f);
    float* so = sco + (size_t)b * 24576 + (size_t)cell * 96;
    for (int c = wl; c < 96; c += 8) {
        float acc = pw[(size_t)c * 64 + lane] * act;
        for (int m = 1; m < 64; m <<= 1) acc += __shfl_xor(acc, m);
        if (lane == 0) so[c] = acc + pb[c];
    }
}

// ---- apply_k v2: guide + slice (y-prereduced LDS) + affine apply ------------
// One block per 32x32-px tile (grid = B*1024); 4 px/thread via float4.
// Constant (fy,fx) per tile -> 2x2 cell footprint. Per-row y-interp is
// pre-reduced into R[row][dx][z*12+c] (padded stride) so the px loop reads
// only 4 corners (2 dz x 2 dx) = 12 ds_read_b128 instead of 24.
#define RSTRIDE 196   // 2*96 + 4 pad (floats); row base stays 16B-aligned
__global__ __launch_bounds__(256, 4) void apply_k(
    const float* __restrict__ img, const float* __restrict__ sco,
    const float* __restrict__ ccm_w, const float* __restrict__ ccm_b,
    const float* __restrict__ shifts, const float* __restrict__ slopes,
    const float* __restrict__ proj_w, const float* __restrict__ proj_b,
    float* __restrict__ out) {
    __shared__ __align__(16) float s_sco[4 * 96];     // 2x2 cells x 96
    __shared__ __align__(16) float s_R[32 * RSTRIDE]; // per-row y-interp

    const int t   = threadIdx.x;
    const int b   = blockIdx.x >> 10;
    const int rem = blockIdx.x & 1023;
    const int ty  = rem >> 5;
    const int tx  = rem & 31;
    const int fy0 = (ty - 1) >> 1;
    const int fx0 = (tx - 1) >> 1;

    // stage 2x2 cells (96 float4)
    if (t < 96) {
        int cell = t / 24;          // dy*2+dx
        int i4 = t % 24;
        int dy = cell >> 1, dx = cell & 1;
        int gy = min(max(fy0 + dy, 0), 15);
        int gx = min(max(fx0 + dx, 0), 15);
        float4 v = ((const float4*)(sco + ((size_t)b * 256 + gy * 16 + gx) * 96))[i4];
        ((float4*)(s_sco + cell * 96))[i4] = v;
    }
    __syncthreads();

    // build R: 32 rows x 2 dx x 24 float4; R[row][dx] = wy0*A[0][dx] + wy1*A[1][dx]
    for (int idx = t; idx < 1536; idx += 256) {
        int q = idx % 24;
        int rowdx = idx / 24;
        int row = rowdx >> 1, dx = rowdx & 1;
        float ys = ((float)(ty * 32 + row) + 0.5f) * 0.015625f - 0.5f;
        float wy1 = ys - (float)fy0;
        float wy0 = 1.0f - wy1;
        float4 a0 = ((const float4*)(s_sco + dx * 96))[q];         // dy=0
        float4 a1 = ((const float4*)(s_sco + (2 + dx) * 96))[q];   // dy=1
        float4 v = make_float4(wy0 * a0.x + wy1 * a1.x, wy0 * a0.y + wy1 * a1.y,
                               wy0 * a0.z + wy1 * a1.z, wy0 * a0.w + wy1 * a1.w);
        ((float4*)(s_R + row * RSTRIDE + dx * 96))[q] = v;
    }
    __syncthreads();

    const size_t plane = 1024 * 1024;
    const float* ibase = img + (size_t)b * 3 * plane;
    float* obase = out + (size_t)b * 3 * plane;

    const int row = t >> 3;                  // 0..31
    const int xg  = (t & 7) * 4;
    const int y = ty * 32 + row;
    const int x0 = tx * 32 + xg;
    const size_t off = (size_t)y * 1024 + x0;

    float4 r4 = *(const float4*)(ibase + off);
    float4 g4 = *(const float4*)(ibase + plane + off);
    float4 b4 = *(const float4*)(ibase + 2 * plane + off);
    const float rj[4] = { r4.x, r4.y, r4.z, r4.w };
    const float gj[4] = { g4.x, g4.y, g4.z, g4.w };
    const float bj[4] = { b4.x, b4.y, b4.z, b4.w };

    const float* Rrow = s_R + row * RSTRIDE;
    float o_r[4], o_g[4], o_b[4];

#pragma unroll
    for (int j = 0; j < 4; ++j) {
        float r = rj[j], g = gj[j], bl = bj[j];

        // ---- guide (uniform params -> SGPR s_loads) ----
        float gd = proj_b[0];
#pragma unroll
        for (int c = 0; c < 3; ++c) {
            float v = ccm_b[c] + ccm_w[c * 3 + 0] * r + ccm_w[c * 3 + 1] * g + ccm_w[c * 3 + 2] * bl;
            float acc = 0.0f;
#pragma unroll
            for (int p = 0; p < 16; ++p)
                acc += slopes[c * 16 + p] * fmaxf(v - shifts[c * 16 + p], 0.0f);
            gd += proj_w[c] * acc;
        }
        gd = fminf(fmaxf(gd, 0.0f), 1.0f);

        // ---- slice weights ----
        float xs = ((float)(x0 + j) + 0.5f) * 0.015625f - 0.5f;
        float wx1 = xs - (float)fx0;
        float wx0 = 1.0f - wx1;
        float gz = gd * 8.0f - 0.5f;
        float fzf = floorf(gz);
        int fz = (int)fzf;
        float wz1 = gz - fzf;
        float wz0 = 1.0f - wz1;

        float ar = 0.0f, ag = 0.0f, ab = 0.0f;
#pragma unroll
        for (int dz = 0; dz < 2; ++dz) {
            int zi = min(max(fz + dz, 0), 7);
            float wz = dz ? wz1 : wz0;
#pragma unroll
            for (int dx = 0; dx < 2; ++dx) {
                float wt = wz * (dx ? wx1 : wx0);
                const float4* gp = (const float4*)(Rrow + dx * 96 + zi * 12);
                float4 a0 = gp[0], a1 = gp[1], a2 = gp[2];
                ar += wt * (a0.x * r + a0.y * g + a0.z * bl + a0.w);
                ag += wt * (a1.x * r + a1.y * g + a1.z * bl + a1.w);
                ab += wt * (a2.x * r + a2.y * g + a2.z * bl + a2.w);
            }
        }
        o_r[j] = fminf(fmaxf(ar, 0.0f), 1.0f);
        o_g[j] = fminf(fmaxf(ag, 0.0f), 1.0f);
        o_b[j] = fminf(fmaxf(ab, 0.0f), 1.0f);
    }

    *(float4*)(obase + off)             = make_float4(o_r[0], o_r[1], o_r[2], o_r[3]);
    *(float4*)(obase + plane + off)     = make_float4(o_g[0], o_g[1], o_g[2], o_g[3]);
    *(float4*)(obase + 2 * plane + off) = make_float4(o_b[0], o_b[1], o_b[2], o_b[3]);
}

// ---------------------------------------------------------------------------

extern "C" void kernel_launch(void* const* d_in, const int* in_sizes, int n_in,
                              void* d_out, int out_size, void* d_ws, size_t ws_size,
                              hipStream_t stream) {
    const float* img_lo = (const float*)d_in[0];
    const float* img_fr = (const float*)d_in[1];
    const float* sw0 = (const float*)d_in[2];  const float* sb0 = (const float*)d_in[3];
    const float* sw1 = (const float*)d_in[4];  const float* sb1 = (const float*)d_in[5];
    const float* sw2 = (const float*)d_in[6];  const float* sb2 = (const float*)d_in[7];
    const float* sw3 = (const float*)d_in[8];  const float* sb3 = (const float*)d_in[9];
    const float* gw0 = (const float*)d_in[10]; const float* gb0 = (const float*)d_in[11];
    const float* gw1 = (const float*)d_in[12]; const float* gb1 = (const float*)d_in[13];
    const float* fw0 = (const float*)d_in[14]; const float* fb0 = (const float*)d_in[15];
    const float* fw1 = (const float*)d_in[16]; const float* fb1 = (const float*)d_in[17];
    const float* fw2 = (const float*)d_in[18]; const float* fb2 = (const float*)d_in[19];
    const float* lw0 = (const float*)d_in[20]; const float* lb0 = (const float*)d_in[21];
    const float* lw1 = (const float*)d_in[22];
    const float* pw  = (const float*)d_in[23]; const float* pb  = (const float*)d_in[24];
    const float* ccm_w  = (const float*)d_in[25]; const float* ccm_b = (const float*)d_in[26];
    const float* shifts = (const float*)d_in[27];
    const float* slopes = (const float*)d_in[28];
    const float* proj_w = (const float*)d_in[29];
    const float* proj_b = (const float*)d_in[30];
    float* out = (float*)d_out;

    const int B = in_sizes[0] / (3 * 256 * 256);   // = 2

    // workspace carve (floats)
    float* ws = (float*)d_ws;
    float* x0   = ws;                                // B*8*128*128   CHW
    float* x1   = x0 + (size_t)B * 8  * 128 * 128;   // B*16*64*64    CHW
    float* x2   = x1 + (size_t)B * 16 * 64 * 64;     // B*32*32*32    HWC
    float* x3   = x2 + (size_t)B * 32 * 32 * 32;     // B*16*16*64    HWC
    float* g0   = x3 + (size_t)B * 64 * 16 * 16;     // B*8*8*64      HWC
    float* g1   = g0 + (size_t)B * 64 * 8 * 8;       // B*64*4*4      CHW
    float* f0   = g1 + (size_t)B * 64 * 4 * 4;       // B*256
    float* loc0 = f0 + (size_t)B * 256;              // B*16*16*64    HWC
    float* loc1 = loc0 + (size_t)B * 64 * 16 * 16;   // B*16*16*64    HWC
    float* sco  = loc1 + (size_t)B * 64 * 16 * 16;   // B*256*96

    const int T = 256;

    // 1-3: splat chain (wide)
    conv3x3_chw_k<<<cdiv(B * 8 * 128 * 128, T), T, 0, stream>>>(img_lo, sw0, sb0, x0, B, 3, 256, 256, 8, 128, 128, 2);
    conv3x3_chw_k<<<cdiv(B * 16 * 64 * 64, T), T, 0, stream>>>(x0, sw1, sb1, x1, B, 8, 128, 128, 16, 64, 64, 2);
    conv3x3_hwc_k<<<cdiv(B * 32 * 32 * 32, T), T, 0, stream>>>(x1, sw2, sb2, x2, B, 16, 64, 64, 32, 32, 32, 2);
    // 4: conv3 (wave)
    conv3_k<<<cdiv(B * 32 * 16 * 16 * 64, T), T, 0, stream>>>(x2, sw3, sb3, x3, B);
    // 5: gconv0 || lconv0
    {
        int nwaves = B * 64 * 8 * 8 + B * 64 * 16 * 16;
        gl0_k<<<cdiv(nwaves * 64, T), T, 0, stream>>>(x3, gw0, gb0, g0, lw0, lb0, loc0, B);
    }
    // 6: gconv1 || lconv1
    {
        int nwaves = B * 64 * 4 * 4 + B * 64 * 16 * 16;
        gl1_k<<<cdiv(nwaves * 64, T), T, 0, stream>>>(g0, loc0, gw1, gb1, g1, lw1, loc1, B);
    }
    // 7: fc0 (wide, wave per output)
    fc0_k<<<cdiv(B * 256 * 64, T), T, 0, stream>>>(g1, fw0, fb0, f0, B);
    // 8: fc1+fc2+pred -> sco (one cell per block, 8 waves)
    pred_k<<<B * 256, 512, 0, stream>>>(f0, fw1, fb1, fw2, fb2, loc1, pw, pb, sco);
    // 9: guide + slice + apply (32x32-px tiles, y-prereduced LDS)
    apply_k<<<B * 1024, 256, 0, stream>>>(img_fr, sco, ccm_w, ccm_b, shifts, slopes,
                                          proj_w, proj_b, out);
}